// Round 6
// baseline (59.798 us; speedup 1.0000x reference)
//
#include <hip/hip_runtime.h>

// DenseByItems: out[b,k] = dot(V[items[b,k]], seq[b]) + B[items[b,k]]
// seq: [4096,128] f32, items: [4096,200] i32, V: [100000,128] f32, B: [100000,1] f32
//
// Round 6: keep bf16-V + XCD-slice (fixed memory wall, r4/r5); replace the
// scalar dot-product machinery (VALU-issue wall, ~28 insts/item-lane) with
// mfma_f32_16x16x32_bf16: 16 items/set, B = seq[b] broadcast to all 16 cols,
// D cols all equal = scores. Per set: 4 gathers + 4 MFMAs + bookkeeping.

#define BATCH 4096
#define KITEMS 200
#define DIM 128
#define NITEMS 100000
#define NSLICE 8
#define SLICE_ROWS (NITEMS / NSLICE)   // 12500
#define GB 16                          // b's per block (one per 16-lane group)

typedef __attribute__((ext_vector_type(8))) short bf16x8;
typedef __attribute__((ext_vector_type(4))) float f32x4;

__device__ __forceinline__ unsigned short f2bf(float f) {
    unsigned u = __float_as_uint(f);
    u += 0x7fffu + ((u >> 16) & 1u);   // round-to-nearest-even
    return (unsigned short)(u >> 16);
}

// ---- K1: V -> Vh (bf16) and seq -> seqh (bf16), both in workspace ----------
#define NV_VEC (NITEMS * DIM / 8)      // 1,600,000 uint4 outputs (6250 blocks)
#define NS_VEC (BATCH * DIM / 8)       // 65,536   uint4 outputs (256 blocks)
__global__ __launch_bounds__(256) void convert_kernel(
    const float* __restrict__ V, const float* __restrict__ seq,
    unsigned short* __restrict__ Vh, unsigned short* __restrict__ seqh) {
    int i = blockIdx.x * 256 + threadIdx.x;
    const float4* src;
    uint4* dst;
    if (i < NV_VEC) {
        src = reinterpret_cast<const float4*>(V) + (size_t)i * 2;
        dst = reinterpret_cast<uint4*>(Vh) + i;
    } else {
        i -= NV_VEC;                    // exact: grid = 6250 + 256 blocks
        src = reinterpret_cast<const float4*>(seq) + (size_t)i * 2;
        dst = reinterpret_cast<uint4*>(seqh) + i;
    }
    const float4 a = src[0];
    const float4 b = src[1];
    union { unsigned short h[8]; uint4 u; } pk;
    pk.h[0] = f2bf(a.x); pk.h[1] = f2bf(a.y); pk.h[2] = f2bf(a.z); pk.h[3] = f2bf(a.w);
    pk.h[4] = f2bf(b.x); pk.h[5] = f2bf(b.y); pk.h[6] = f2bf(b.z); pk.h[7] = f2bf(b.w);
    *dst = pk.u;
}

// ---- K2: main — filter + MFMA scoring --------------------------------------
__global__ __launch_bounds__(256, 4) void main_mfma_kernel(
    const int* __restrict__ items,          // [BATCH, KITEMS]
    const unsigned short* __restrict__ Vh,  // [NITEMS, DIM] bf16
    const unsigned short* __restrict__ seqh,// [BATCH, DIM] bf16
    const float* __restrict__ Bias,         // [NITEMS]
    float* __restrict__ out)                // [BATCH, KITEMS]
{
    const unsigned bid = blockIdx.x;
    const int s  = bid & 7;      // slice == XCD id under round-robin dispatch (perf heuristic)
    const int g  = bid >> 3;     // 0..255
    const int lo = s * SLICE_ROWS;
    const int hi = lo + SLICE_ROWS;

    const int tid  = threadIdx.x;
    const int lane = tid & 63;
    const int wv   = tid >> 6;   // wave 0..3
    const int sub  = lane & 15;  // lane within 16-group
    const int gw   = lane >> 4;  // 16-group within wave (0..3)
    const int gid  = wv * 4 + gw;

    __shared__ __align__(16) int s_list[GB][KITEMS];  // (item<<8)|k, k-ascending

    // ---- filter: each 16-lane group compacts its own b (no atomics/barriers)
    const int bF = g * GB + gid;
    const int* itb = items + (size_t)bF * KITEMS;
    int n = 0;
    #pragma unroll
    for (int r = 0; r < 13; ++r) {                    // 13*16 = 208 >= 200
        const int k = r * 16 + sub;
        int it = 0;
        bool pred = false;
        if (k < KITEMS) {
            it = itb[k];
            pred = (it >= lo) & (it < hi);
        }
        const unsigned long long bal = __ballot(pred);
        const unsigned m16 = (unsigned)(bal >> (gw * 16)) & 0xffffu;
        if (pred) {
            s_list[gid][n + __popc(m16 & ((1u << sub) - 1u))] = (it << 8) | k;
        }
        n += __popc(m16);                             // uniform within the group
    }
    // lists are wave-private (wave wv wrote gid = wv*4 + gw) -> no __syncthreads

    // ---- process: wave wv scores b's {4wv..4wv+3} sequentially via MFMA ----
    for (int bb = 0; bb < 4; ++bb) {
        const int nb  = __shfl(n, bb * 16);           // n of group bb (uniform there)
        if (nb == 0) continue;
        const int lid = wv * 4 + bb;
        const int b   = g * GB + lid;

        // B fragments: lane holds seqh[b, kk*32 + gw*8 .. +8) for kk=0..3.
        // All 16 cols identical -> every D column = score vector.
        const unsigned short* sq = seqh + (size_t)b * DIM + gw * 8;
        bf16x8 Bf[4];
        #pragma unroll
        for (int kk = 0; kk < 4; ++kk)
            Bf[kk] = *reinterpret_cast<const bf16x8*>(sq + kk * 32);

        const int nsets = (nb + 15) >> 4;
        for (int jset = 0; jset < nsets; ++jset) {
            const int jbase = jset << 4;
            const int pos   = jbase + sub;
            // A row for this lane: item at list position jbase+sub (clamped).
            int entry = s_list[lid][pos];             // stale beyond nb -> clamp
            const int it = (pos < nb) ? (entry >> 8) : lo;
            const unsigned short* rowp = Vh + (size_t)it * DIM + gw * 8;

            f32x4 acc = {0.f, 0.f, 0.f, 0.f};
            #pragma unroll
            for (int kk = 0; kk < 4; ++kk) {
                const bf16x8 Af = *reinterpret_cast<const bf16x8*>(rowp + kk * 32);
                acc = __builtin_amdgcn_mfma_f32_16x16x32_bf16(Af, Bf[kk], acc, 0, 0, 0);
            }

            // Writers: lanes sub==0 own rows gw*4 + r in acc[r] (D: col=lane&15,
            // row=(lane>>4)*4+reg — HW-verified mapping).
            if (sub == 0) {
                const int pbase = jbase + gw * 4;
                const int4 e4 = *reinterpret_cast<const int4*>(&s_list[lid][pbase]);
                #pragma unroll
                for (int r = 0; r < 4; ++r) {
                    if (pbase + r < nb) {
                        const int e    = (&e4.x)[r];
                        const int kout = e & 0xff;
                        const int itr  = e >> 8;
                        out[(size_t)b * KITEMS + kout] = acc[r] + Bias[itr];
                    }
                }
            }
        }
    }
}

// ---- fallback (ws too small): r5-style fp32 sliced kernel ------------------
__global__ __launch_bounds__(256) void fallback_kernel(
    const float* __restrict__ seq, const int* __restrict__ items,
    const float* __restrict__ V, const float* __restrict__ Bias,
    float* __restrict__ out)
{
    const unsigned bid = blockIdx.x;
    const int s = bid & 7;
    const int g = bid >> 3;
    const int lo = s * SLICE_ROWS, hi = lo + SLICE_ROWS;
    const int tid = threadIdx.x;
    const int lane = tid & 63;
    const int sub = lane & 15;
    const int gw = lane >> 4;
    const int gid = ((tid >> 6) << 2) + gw;
    const int b = g * GB + gid;

    __shared__ int s_list[GB][KITEMS];
    const int* itb = items + (size_t)b * KITEMS;
    int n = 0;
    #pragma unroll
    for (int r = 0; r < 13; ++r) {
        const int k = r * 16 + sub;
        int it = 0;
        bool pred = false;
        if (k < KITEMS) { it = itb[k]; pred = (it >= lo) & (it < hi); }
        const unsigned long long bal = __ballot(pred);
        const unsigned m16 = (unsigned)(bal >> (gw * 16)) & 0xffffu;
        if (pred) s_list[gid][n + __popc(m16 & ((1u << sub) - 1u))] = (it << 8) | k;
        n += __popc(m16);
    }
    const float4* seqr = reinterpret_cast<const float4*>(seq + (size_t)b * DIM);
    const float4 q0 = seqr[2 * sub];
    const float4 q1 = seqr[2 * sub + 1];
    float* outb = out + (size_t)b * KITEMS;
    for (int j = 0; j < n; ++j) {
        const int pk = s_list[gid][j];
        const int it = pk >> 8, k = pk & 0xff;
        const float4* vr = reinterpret_cast<const float4*>(V + (size_t)it * DIM);
        const float4 a0 = vr[2 * sub], a1 = vr[2 * sub + 1];
        float p = q0.x * a0.x + q0.y * a0.y + q0.z * a0.z + q0.w * a0.w
                + q1.x * a1.x + q1.y * a1.y + q1.z * a1.z + q1.w * a1.w;
        p += __shfl_xor(p, 1);
        p += __shfl_xor(p, 2);
        p += __shfl_xor(p, 4);
        p += __shfl_xor(p, 8);
        if (sub == 0) outb[k] = p + Bias[it];
    }
}

extern "C" void kernel_launch(void* const* d_in, const int* in_sizes, int n_in,
                              void* d_out, int out_size, void* d_ws, size_t ws_size,
                              hipStream_t stream) {
    const float* seq   = (const float*)d_in[0];
    const int*   items = (const int*)d_in[1];
    const float* V     = (const float*)d_in[2];
    const float* Bias  = (const float*)d_in[3];
    float*       out   = (float*)d_out;

    const size_t vh_bytes  = (size_t)NITEMS * DIM * sizeof(unsigned short); // 25,600,000
    const size_t sh_bytes  = (size_t)BATCH * DIM * sizeof(unsigned short);  // 1,048,576
    const int grid_main = (BATCH / GB) * NSLICE;  // 2048

    if (ws_size >= vh_bytes + sh_bytes) {
        unsigned short* Vh   = (unsigned short*)d_ws;
        unsigned short* seqh = (unsigned short*)((char*)d_ws + vh_bytes);  // 256B-aligned
        convert_kernel<<<dim3((NV_VEC + NS_VEC) / 256), dim3(256), 0, stream>>>(V, seq, Vh, seqh);
        main_mfma_kernel<<<dim3(grid_main), dim3(256), 0, stream>>>(items, Vh, seqh, Bias, out);
    } else {
        fallback_kernel<<<dim3(grid_main), dim3(256), 0, stream>>>(seq, items, V, Bias, out);
    }
}